// Round 13
// baseline (113.637 us; speedup 1.0000x reference)
//
#include <hip/hip_runtime.h>

typedef __bf16 bf16x8 __attribute__((ext_vector_type(8)));
typedef float f32x4 __attribute__((ext_vector_type(4)));
typedef unsigned int u32;
typedef unsigned short u16;

#define PDIM 528                    // padded image dim (rows -7.., cols -8..)
#define PIMG (PDIM * PDIM)          // per-sample padded elems
#define ROW_B   112                 // bytes per row within one copy (56 slots)
#define COPY_B  (31 * ROW_B)        // 3472 B per copy
#define NCVT 2178                   // cvtpad blocks: 16*528*66/256

__device__ __forceinline__ u16 f2bf(float f) {
    u32 u = __builtin_bit_cast(u32, f);
    return (u16)((u + 0x7FFFu + ((u >> 16) & 1u)) >> 16);  // RNE
}
__device__ __forceinline__ int refl(int i) {  // reflect into [0,512)
    return i < 0 ? -i : (i > 511 ? 1022 - i : i);
}

// ---------- unified pre-pass: pad image + pack weights ----------
__global__ __launch_bounds__(256) void prepass(const float* __restrict__ x,
                                               const float* __restrict__ kern,
                                               u16* __restrict__ P,
                                               uint4* __restrict__ afragG) {
    if (blockIdx.x < NCVT) {
        // P[n][pr][pc] = bf16(x[n,0,refl(pr-7),refl(pc-8)])
        const int u  = blockIdx.x * 256 + threadIdx.x;   // 16*528*66 units
        const int n  = u / (PDIM * 66);
        const int r  = u - n * (PDIM * 66);
        const int pr = r / 66;
        const int cs = r - pr * 66;
        const int pc0 = cs * 8;
        const float* sx = x + (size_t)n * (16u * 512u * 512u)
                          + (size_t)refl(pr - 7) * 512;
        const int g0 = pc0 - 8;
        float v[8];
        if (g0 >= 0 && g0 <= 504) {
            const float4 a = *(const float4*)(sx + g0);
            const float4 b = *(const float4*)(sx + g0 + 4);
            v[0] = a.x; v[1] = a.y; v[2] = a.z; v[3] = a.w;
            v[4] = b.x; v[5] = b.y; v[6] = b.z; v[7] = b.w;
        } else {
            #pragma unroll
            for (int i = 0; i < 8; ++i) v[i] = sx[refl(g0 + i)];
        }
        uint4 q;
        q.x = (u32)f2bf(v[0]) | ((u32)f2bf(v[1]) << 16);
        q.y = (u32)f2bf(v[2]) | ((u32)f2bf(v[3]) << 16);
        q.z = (u32)f2bf(v[4]) | ((u32)f2bf(v[5]) << 16);
        q.w = (u32)f2bf(v[6]) | ((u32)f2bf(v[7]) << 16);
        *(uint4*)(P + (size_t)n * PIMG + (size_t)pr * PDIM + pc0) = q;
    } else {
        // afragG[n][ks][lane]: kh = 2*ks + (g>>1), kw = 8*(g&1) + j
        const int u = (blockIdx.x - NCVT) * 256 + threadIdx.x;  // 8192 units
        const int n    = u >> 9;
        const int rem  = u & 511;
        const int ks   = rem >> 6;
        const int lane = rem & 63;
        const int oca = lane & 15, g = lane >> 4, g1 = g & 1, g2 = g >> 1;
        const float* kp = kern + ((size_t)n * 16 + oca) * 225;
        const int kh = 2 * ks + g2;
        u16 b[8];
        #pragma unroll
        for (int j = 0; j < 8; ++j) {
            const int kw = 8 * g1 + j;
            b[j] = f2bf((kh < 15 && kw < 15) ? kp[kh * 15 + kw] : 0.f);
        }
        uint4 q;
        q.x = (u32)b[0] | ((u32)b[1] << 16);
        q.y = (u32)b[2] | ((u32)b[3] << 16);
        q.z = (u32)b[4] | ((u32)b[5] << 16);
        q.w = (u32)b[6] | ((u32)b[7] << 16);
        afragG[u] = q;
    }
}

// ---------- conv passes ----------
// Block (bx,by,bz): sample n=bz, rows h0=by*16..+15, cols c0=bx*32..+31, 16 oc.
// Wave w owns cols [c0+8w, c0+8w+8) via t=0..7; acc[8] f32x4.
// K = 15x15 padded to 16x16 = 8 MFMA K-steps (HW-validated mapping):
// k = 32*ks + 8*g + j -> kh = 2*ks + (g>>1), kw = 8*(g&1) + j   (g = lane>>4)
// B-fragment (ks,t) = staged elems X..X+7 of row hh+g2+2ks, X = 8*(wave+g1)+t+1.
// LDS holds 4 shifted copies (shift c elems); copy c slot s = elem s+c
// -> fragment = direct ds_read at immediate offset, ZERO inner-loop VALU.
// MODE 0: per-block max -> partial.  MODE 1: reduce partials, scale, store.
template <int MODE>
__global__ __launch_bounds__(256) void dynconv(const u16* __restrict__ P,
                                               const uint4* __restrict__ afragG,
                                               float* __restrict__ out,
                                               float* __restrict__ partial) {
    __shared__ __align__(16) char lds4[4 * COPY_B];   // 13888 B
    __shared__ float wm[4];

    const int tid  = threadIdx.x;
    const int lane = tid & 63;
    const int wave = tid >> 6;
    const int c0 = blockIdx.x * 32;
    const int h0 = blockIdx.y * 16;
    const int n  = blockIdx.z;

    // ---- stage 4 shifted copies: unit (rr, cs) = slots 8cs..8cs+7 all copies ----
    if (tid < 31 * 6) {
        const int rr = tid / 6;
        const int cs = tid - rr * 6;
        const u16* src = P + (size_t)n * PIMG + (size_t)(h0 + rr) * PDIM + c0 + 8 * cs;
        const uint4 A = *(const uint4*)(src);       // elems 8cs+0..7  (vs window)
        const uint4 B = *(const uint4*)(src + 8);   // elems 8cs+8..15
        const u32 W[6] = {A.x, A.y, A.z, A.w, B.x, B.y};
        char* dst = lds4 + rr * ROW_B + 16 * cs;
        uint4 q0, q1, q2, q3;
        q0.x = W[0]; q0.y = W[1]; q0.z = W[2]; q0.w = W[3];
        q1.x = __builtin_amdgcn_alignbit(W[1], W[0], 16);
        q1.y = __builtin_amdgcn_alignbit(W[2], W[1], 16);
        q1.z = __builtin_amdgcn_alignbit(W[3], W[2], 16);
        q1.w = __builtin_amdgcn_alignbit(W[4], W[3], 16);
        q2.x = W[1]; q2.y = W[2]; q2.z = W[3]; q2.w = W[4];
        q3.x = __builtin_amdgcn_alignbit(W[2], W[1], 16);
        q3.y = __builtin_amdgcn_alignbit(W[3], W[2], 16);
        q3.z = __builtin_amdgcn_alignbit(W[4], W[3], 16);
        q3.w = __builtin_amdgcn_alignbit(W[5], W[4], 16);
        *(uint4*)(dst)              = q0;
        *(uint4*)(dst + COPY_B)     = q1;
        *(uint4*)(dst + 2 * COPY_B) = q2;
        *(uint4*)(dst + 3 * COPY_B) = q3;
    }

    // ---- A fragments: 8 coalesced b128 loads from packed table ----
    const int g  = lane >> 4;
    const int g1 = g & 1;
    const int g2 = g >> 1;
    bf16x8 afrag[8];
    {
        const uint4* ap = afragG + ((size_t)n << 9) + lane;   // [n][ks][lane]
        #pragma unroll
        for (int ks = 0; ks < 8; ++ks)
            afrag[ks] = __builtin_bit_cast(bf16x8, ap[ks << 6]);
    }

    // ---- MODE 1: per-sample max from this sample's 512 partials ----
    float scale = 0.f;
    if constexpr (MODE == 1) {
        const float* pp = partial + n * 512 + lane * 8;
        const float4 a = *(const float4*)pp;
        const float4 b = *(const float4*)(pp + 4);
        float pv = fmaxf(fmaxf(fmaxf(a.x, a.y), fmaxf(a.z, a.w)),
                         fmaxf(fmaxf(b.x, b.y), fmaxf(b.z, b.w)));
        #pragma unroll
        for (int off = 32; off > 0; off >>= 1) pv = fmaxf(pv, __shfl_xor(pv, off, 64));
        scale = 1.0f / pv;
    }

    __syncthreads();

    // ---- conv: pure ds_read + MFMA inner loop ----
    const int hh = lane & 15;
    const char* lb = lds4 + (hh + g2) * ROW_B + 16 * (wave + g1);

    f32x4 acc[8];
    #pragma unroll
    for (int t = 0; t < 8; ++t) acc[t] = f32x4{0.f, 0.f, 0.f, 0.f};

    #pragma unroll
    for (int ks = 0; ks < 8; ++ks) {
        #pragma unroll
        for (int t = 0; t < 8; ++t) {
            const int s  = t + 1;
            const int c  = s & 3;
            const int sh = s - c;                         // 0, 4, or 8
            const int off = c * COPY_B + ks * (2 * ROW_B) + 2 * sh;
            uint4 dv;
            if ((sh & 4) == 0) {                          // 16B-aligned: one b128
                dv = *(const uint4*)(lb + off);
            } else {                                      // 8B-aligned: two b64
                const uint2 lo = *(const uint2*)(lb + off);
                const uint2 hi = *(const uint2*)(lb + off + 8);
                dv.x = lo.x; dv.y = lo.y; dv.z = hi.x; dv.w = hi.y;
            }
            acc[t] = __builtin_amdgcn_mfma_f32_16x16x32_bf16(
                afrag[ks], __builtin_bit_cast(bf16x8, dv), acc[t], 0, 0, 0);
        }
    }

    if constexpr (MODE == 0) {
        float m = -3.4e38f;
        #pragma unroll
        for (int t = 0; t < 8; ++t)
            #pragma unroll
            for (int r = 0; r < 4; ++r) m = fmaxf(m, acc[t][r]);
        #pragma unroll
        for (int off = 32; off > 0; off >>= 1) m = fmaxf(m, __shfl_xor(m, off, 64));
        if (lane == 0) wm[wave] = m;
        __syncthreads();
        if (tid == 0)
            partial[n * 512 + blockIdx.y * 16 + blockIdx.x] =
                fmaxf(fmaxf(wm[0], wm[1]), fmaxf(wm[2], wm[3]));
    } else {
        // ---- coalesced epilogue: transpose through LDS (XOR-swizzled) ----
        __shared__ __align__(16) float lout[4 * 16 * 36];     // 9216 B
        const int oh_w  = g * 16 + hh;
        float* wp = &lout[oh_w * 36 + ((8 * wave) ^ (8 * (oh_w & 3)))];
        const int oh_r = tid >> 2;
        const int ci   = (tid & 3) * 8;
        const float* rp = &lout[oh_r * 36 + (ci ^ (8 * (oh_r & 3)))];
        const int oc2 = oh_r >> 4, h2 = oh_r & 15;

        #pragma unroll
        for (int r = 0; r < 4; ++r) {
            __syncthreads();
            f32x4 v0, v1;
            v0[0] = acc[0][r] * scale; v0[1] = acc[1][r] * scale;
            v0[2] = acc[2][r] * scale; v0[3] = acc[3][r] * scale;
            v1[0] = acc[4][r] * scale; v1[1] = acc[5][r] * scale;
            v1[2] = acc[6][r] * scale; v1[3] = acc[7][r] * scale;
            *(f32x4*)wp       = v0;
            *(f32x4*)(wp + 4) = v1;
            __syncthreads();
            const f32x4 s0 = *(const f32x4*)rp;
            const f32x4 s1 = *(const f32x4*)(rp + 4);
            float* orow = out + (((size_t)((4 * oc2 + r) * 16 + n)) * 512
                                 + (size_t)(h0 + h2)) * 512 + c0 + ci;
            *(f32x4*)orow       = s0;
            *(f32x4*)(orow + 4) = s1;
        }
    }
}

extern "C" void kernel_launch(void* const* d_in, const int* in_sizes, int n_in,
                              void* d_out, int out_size, void* d_ws, size_t ws_size,
                              hipStream_t stream) {
    (void)in_sizes; (void)n_in; (void)out_size; (void)ws_size;
    const float* x  = (const float*)d_in[0];
    const float* k  = (const float*)d_in[1];
    float* out      = (float*)d_out;
    u16* P          = (u16*)d_ws;                               // 8.92 MB padded bf16
    uint4* afragG   = (uint4*)((char*)d_ws + (10u << 20));      // 128 KB packed weights
    float* partial  = (float*)((char*)d_ws + (12u << 20));      // 32 KB partial maxima

    prepass<<<dim3(NCVT + 32), dim3(256), 0, stream>>>(x, k, P, afragG);
    dim3 grid(16, 32, 16);   // 32-col x 16-row x sample = 8192 blocks
    dim3 block(256);
    dynconv<0><<<grid, block, 0, stream>>>(P, afragG, out, partial);  // max pass
    dynconv<1><<<grid, block, 0, stream>>>(P, afragG, out, partial);  // scale+store
}